// Round 1
// baseline (553.840 us; speedup 1.0000x reference)
//
#include <hip/hip_runtime.h>
#include <hip/hip_bf16.h>
#include <stdint.h>

#define N_ROWS 131072
#define K_CL   512
#define D_DIM  512
#define M_TILE 32
#define BK     32
#define STEPS  (D_DIM / BK)   // 16

typedef __attribute__((ext_vector_type(8))) short short8;
typedef __attribute__((ext_vector_type(4))) float f32x4;

__device__ __forceinline__ unsigned short f2bf(float f) {
  union { float f; unsigned u; } v; v.f = f;
  unsigned r = v.u + 0x7fffu + ((v.u >> 16) & 1u);
  return (unsigned short)(r >> 16);
}

// --- prep 1: c2 = ||c||^2 per cluster row ---
__global__ void prep_c2(const float* __restrict__ c, float* __restrict__ c2) {
  const int b = blockIdx.x;   // cluster row 0..511
  const int l = threadIdx.x;  // 0..63
  const float* row = c + (size_t)b * D_DIM;
  float s = 0.f;
  #pragma unroll
  for (int i = 0; i < 2; ++i) {
    const int col = i * 256 + l * 4;
    float4 v = *(const float4*)(row + col);
    s += v.x * v.x + v.y * v.y + v.z * v.z + v.w * v.w;
  }
  #pragma unroll
  for (int m = 1; m < 64; m <<= 1) s += __shfl_xor(s, m);
  if (l == 0) c2[b] = s;
}

// --- prep 2: pack clusters fp32 -> bf16 in MFMA B-fragment order ---
// pb[(kk*32 + c16)*64 + lane] (16B each) = B[c16*16 + (lane&15)][kk*32 + (lane>>4)*8 + j]
__global__ void pack_b(const float* __restrict__ c, unsigned short* __restrict__ pb) {
  const int bid = blockIdx.x;       // = kk*32 + c16, 0..511
  const int c16 = bid & 31;
  const int kk  = bid >> 5;
  const int l   = threadIdx.x;      // 0..63
  const int row = c16 * 16 + (l & 15);
  const int k0  = kk * 32 + (l >> 4) * 8;
  float4 v0 = *(const float4*)(c + (size_t)row * D_DIM + k0);
  float4 v1 = *(const float4*)(c + (size_t)row * D_DIM + k0 + 4);
  ushort4 u0 = make_ushort4(f2bf(v0.x), f2bf(v0.y), f2bf(v0.z), f2bf(v0.w));
  ushort4 u1 = make_ushort4(f2bf(v1.x), f2bf(v1.y), f2bf(v1.z), f2bf(v1.w));
  *(ushort4*)(pb + (size_t)(bid * 64 + l) * 8)     = u0;
  *(ushort4*)(pb + (size_t)(bid * 64 + l) * 8 + 4) = u1;
}

// --- main: 32-row x 512-col tile per block; 4 blocks/CU (16 waves) for latency hiding ---
// Per wave: 32 rows x 128 cols -> acc[2][8] = 64 regs/lane (was 128), cap total <=128
// so __launch_bounds__(256,4) doubles resident waves vs the previous version.
__global__ __launch_bounds__(256, 4)
void cluster_main(const float* __restrict__ x,
                  const unsigned short* __restrict__ pb,
                  const float* __restrict__ c2,
                  float* __restrict__ out) {
  __shared__ short As[2][M_TILE * 40];       // double-buffered, padded 32->40
  __shared__ float c2s[K_CL];
  __shared__ float x2s[M_TILE];
  __shared__ float rowsum[4][M_TILE];
  __shared__ float rinv[M_TILE];

  const int t = threadIdx.x;
  const int w = t >> 6;        // wave 0..3 -> col slice [w*128, w*128+128)
  const int l = t & 63;
  const int row0 = blockIdx.x * M_TILE;

  c2s[t] = c2[t];
  c2s[t + 256] = c2[t + 256];

  f32x4 acc[2][8];
  #pragma unroll
  for (int i = 0; i < 2; ++i)
    #pragma unroll
    for (int j = 0; j < 8; ++j) acc[i][j] = (f32x4){0.f, 0.f, 0.f, 0.f};

  // A staging: each thread loads 1 float4 (row rowA, k-offset kc) per K-step
  const int rowA = t >> 3;           // 0..31
  const int kc   = (t & 7) * 4;
  float ss = 0.f;

  const float* xA = x + (size_t)(row0 + rowA) * D_DIM + kc;

  // prologue: prefetch step-0 A into registers
  float4 va = *(const float4*)(xA);

  int cur = 0;
  for (int kk = 0; kk < STEPS; ++kk) {
    // stage current A registers -> LDS, accumulate ||x||^2 in fp32
    ss += va.x * va.x + va.y * va.y + va.z * va.z + va.w * va.w;
    *(ushort4*)&As[cur][rowA * 40 + kc] =
        make_ushort4(f2bf(va.x), f2bf(va.y), f2bf(va.z), f2bf(va.w));

    // register-prefetch next step's A (hides HBM latency behind this step's MFMA)
    if (kk + 1 < STEPS) {
      va = *(const float4*)(xA + (kk + 1) * BK);
    }

    // first half of B fragments issued BEFORE the barrier: L2 latency hides
    // under staging + barrier. Two halves of 4 keep peak live b-regs at 32.
    const unsigned short* pbk = pb + ((size_t)(kk * 32 + w * 8) * 64 + l) * 8;
    short8 bh[4];
    #pragma unroll
    for (int ct = 0; ct < 4; ++ct)
      bh[ct] = *(const short8*)(pbk + (size_t)ct * 64 * 8);

    __syncthreads();  // As[cur] staging visible (single barrier per K-step)

    short8 a0 = *(const short8*)&As[cur][(l & 15) * 40 + (l >> 4) * 8];
    short8 a1 = *(const short8*)&As[cur][(16 + (l & 15)) * 40 + (l >> 4) * 8];

    #pragma unroll
    for (int ct = 0; ct < 4; ++ct) {
      acc[0][ct] = __builtin_amdgcn_mfma_f32_16x16x32_bf16(a0, bh[ct], acc[0][ct], 0, 0, 0);
      acc[1][ct] = __builtin_amdgcn_mfma_f32_16x16x32_bf16(a1, bh[ct], acc[1][ct], 0, 0, 0);
    }

    // second half of B (reuses the 4 b-regs; exposed L2 latency ~160cy is
    // covered by 4 waves/SIMD TLP)
    #pragma unroll
    for (int ct = 0; ct < 4; ++ct)
      bh[ct] = *(const short8*)(pbk + (size_t)(4 + ct) * 64 * 8);

    #pragma unroll
    for (int ct = 0; ct < 4; ++ct) {
      acc[0][4 + ct] = __builtin_amdgcn_mfma_f32_16x16x32_bf16(a0, bh[ct], acc[0][4 + ct], 0, 0, 0);
      acc[1][4 + ct] = __builtin_amdgcn_mfma_f32_16x16x32_bf16(a1, bh[ct], acc[1][4 + ct], 0, 0, 0);
    }

    cur ^= 1;
  }

  // ||x||^2 per row: reduce within 8-lane groups (same row), fp32-exact
  float s1 = ss;
  s1 += __shfl_xor(s1, 1); s1 += __shfl_xor(s1, 2); s1 += __shfl_xor(s1, 4);
  if ((t & 7) == 0) x2s[rowA] = s1;
  __syncthreads();

  const int lg = l >> 4;
  const int ln = l & 15;

  float xr[2][4];
  #pragma unroll
  for (int rt = 0; rt < 2; ++rt)
    #pragma unroll
    for (int r = 0; r < 4; ++r) xr[rt][r] = x2s[rt * 16 + lg * 4 + r];
  float cv[8];
  #pragma unroll
  for (int ct = 0; ct < 8; ++ct) cv[ct] = c2s[w * 128 + ct * 16 + ln];

  float rp[2][4];
  #pragma unroll
  for (int rt = 0; rt < 2; ++rt)
    #pragma unroll
    for (int r = 0; r < 4; ++r) rp[rt][r] = 0.f;

  #pragma unroll
  for (int rt = 0; rt < 2; ++rt)
    #pragma unroll
    for (int ct = 0; ct < 8; ++ct) {
      f32x4 s = acc[rt][ct], q;
      #pragma unroll
      for (int r = 0; r < 4; ++r) {
        float d2 = xr[rt][r] + cv[ct] - 2.f * s[r];
        d2 = fmaxf(d2, 0.f);
        float qq = __builtin_amdgcn_rcpf(1.f + d2);
        q[r] = qq;
        rp[rt][r] += qq;
      }
      acc[rt][ct] = q;
    }

  #pragma unroll
  for (int m = 1; m < 16; m <<= 1)
    #pragma unroll
    for (int rt = 0; rt < 2; ++rt)
      #pragma unroll
      for (int r = 0; r < 4; ++r) rp[rt][r] += __shfl_xor(rp[rt][r], m);

  if (ln == 0)
    #pragma unroll
    for (int rt = 0; rt < 2; ++rt)
      #pragma unroll
      for (int r = 0; r < 4; ++r)
        rowsum[w][rt * 16 + lg * 4 + r] = rp[rt][r];
  __syncthreads();

  if (t < M_TILE) {
    float tot = rowsum[0][t] + rowsum[1][t] + rowsum[2][t] + rowsum[3][t];
    rinv[t] = __builtin_amdgcn_rcpf(tot);
  }
  __syncthreads();

  float ri[2][4];
  #pragma unroll
  for (int rt = 0; rt < 2; ++rt)
    #pragma unroll
    for (int r = 0; r < 4; ++r) ri[rt][r] = rinv[rt * 16 + lg * 4 + r];

  // nontemporal stores: keep the 268 MB write stream from evicting L2-resident pb
  #pragma unroll
  for (int rt = 0; rt < 2; ++rt)
    #pragma unroll
    for (int ct = 0; ct < 8; ++ct)
      #pragma unroll
      for (int r = 0; r < 4; ++r)
        __builtin_nontemporal_store(
            acc[rt][ct][r] * ri[rt][r],
            &out[(size_t)(row0 + rt * 16 + lg * 4 + r) * K_CL + w * 128 + ct * 16 + ln]);
}

extern "C" void kernel_launch(void* const* d_in, const int* in_sizes, int n_in,
                              void* d_out, int out_size, void* d_ws, size_t ws_size,
                              hipStream_t stream) {
  const float* x        = (const float*)d_in[0];
  const float* clusters = (const float*)d_in[1];
  float* out = (float*)d_out;

  // workspace: [pb: 512*512*2B packed bf16][c2: 512*4B]
  unsigned short* pbuf = (unsigned short*)d_ws;
  float* c2 = (float*)((char*)d_ws + (size_t)K_CL * D_DIM * sizeof(unsigned short));

  prep_c2<<<K_CL, 64, 0, stream>>>(clusters, c2);
  pack_b<<<STEPS * 32, 64, 0, stream>>>(clusters, pbuf);
  cluster_main<<<N_ROWS / M_TILE, 256, 0, stream>>>(x, pbuf, c2, out);
}

// Round 2
// 496.929 us; speedup vs baseline: 1.1145x; 1.1145x over previous
//
#include <hip/hip_runtime.h>
#include <hip/hip_bf16.h>
#include <stdint.h>

#define N_ROWS 131072
#define K_CL   512
#define D_DIM  512
#define M_TILE 128
#define BK     32
#define STEPS  (D_DIM / BK)   // 16

typedef __attribute__((ext_vector_type(8))) short short8;
typedef __attribute__((ext_vector_type(4))) float f32x4;

__device__ __forceinline__ unsigned short f2bf(float f) {
  union { float f; unsigned u; } v; v.f = f;
  unsigned r = v.u + 0x7fffu + ((v.u >> 16) & 1u);
  return (unsigned short)(r >> 16);
}

// --- prep 1: c2 = ||c||^2 per cluster row ---
__global__ void prep_c2(const float* __restrict__ c, float* __restrict__ c2) {
  const int b = blockIdx.x;   // cluster row 0..511
  const int l = threadIdx.x;  // 0..63
  const float* row = c + (size_t)b * D_DIM;
  float s = 0.f;
  #pragma unroll
  for (int i = 0; i < 2; ++i) {
    const int col = i * 256 + l * 4;
    float4 v = *(const float4*)(row + col);
    s += v.x * v.x + v.y * v.y + v.z * v.z + v.w * v.w;
  }
  #pragma unroll
  for (int m = 1; m < 64; m <<= 1) s += __shfl_xor(s, m);
  if (l == 0) c2[b] = s;
}

// --- prep 2: pack clusters fp32 -> bf16 in MFMA B-fragment order ---
// pb[(kk*32 + c16)*64 + lane] (16B each) = B[c16*16 + (lane&15)][kk*32 + (lane>>4)*8 + j]
__global__ void pack_b(const float* __restrict__ c, unsigned short* __restrict__ pb) {
  const int bid = blockIdx.x;       // = kk*32 + c16, 0..511
  const int c16 = bid & 31;
  const int kk  = bid >> 5;
  const int l   = threadIdx.x;      // 0..63
  const int row = c16 * 16 + (l & 15);
  const int k0  = kk * 32 + (l >> 4) * 8;
  float4 v0 = *(const float4*)(c + (size_t)row * D_DIM + k0);
  float4 v1 = *(const float4*)(c + (size_t)row * D_DIM + k0 + 4);
  ushort4 u0 = make_ushort4(f2bf(v0.x), f2bf(v0.y), f2bf(v0.z), f2bf(v0.w));
  ushort4 u1 = make_ushort4(f2bf(v1.x), f2bf(v1.y), f2bf(v1.z), f2bf(v1.w));
  *(ushort4*)(pb + (size_t)(bid * 64 + l) * 8)     = u0;
  *(ushort4*)(pb + (size_t)(bid * 64 + l) * 8 + 4) = u1;
}

// --- main: 128-row x 512-col tile per block (512 threads, 8 waves).
// Wave grid 2(row)x4(col): each wave 64 rows x 128 cols, acc[4][8]=128 regs/lane.
// B-L2 traffic = (N/128) * 512KB = 536 MB (half of round-0), and wr=0/1 wave
// pairs read identical B bytes -> second reader hits L1.
__global__ __launch_bounds__(512, 2)
void cluster_main(const float* __restrict__ x,
                  const unsigned short* __restrict__ pb,
                  const float* __restrict__ c2,
                  float* __restrict__ out) {
  __shared__ short As[2][M_TILE * 40];       // double-buffered, padded 32->40
  __shared__ float c2s[K_CL];
  __shared__ float x2s[M_TILE];
  __shared__ float rowsum[4][M_TILE];
  __shared__ float rinv[M_TILE];

  const int t = threadIdx.x;
  const int w  = t >> 6;       // wave 0..7
  const int wr = w >> 2;       // 0..1 -> row half [wr*64, wr*64+64)
  const int wc = w & 3;        // 0..3 -> col slice [wc*128, wc*128+128)
  const int l = t & 63;
  const int row0 = blockIdx.x * M_TILE;

  c2s[t] = c2[t];

  f32x4 acc[4][8];
  #pragma unroll
  for (int i = 0; i < 4; ++i)
    #pragma unroll
    for (int j = 0; j < 8; ++j) acc[i][j] = (f32x4){0.f, 0.f, 0.f, 0.f};

  // A staging: thread loads rows rowA and rowA+64 at k-offset kc (2 float4/step)
  const int rowA = t >> 3;           // 0..63
  const int rowB = rowA + 64;
  const int kc   = (t & 7) * 4;
  float ssA = 0.f, ssB = 0.f;

  const float* xA = x + (size_t)(row0 + rowA) * D_DIM + kc;
  const float* xB = x + (size_t)(row0 + rowB) * D_DIM + kc;

  // prologue: prefetch step-0 A into registers
  float4 va = *(const float4*)(xA);
  float4 vb = *(const float4*)(xB);

  int cur = 0;
  for (int kk = 0; kk < STEPS; ++kk) {
    // stage current A registers -> LDS, accumulate ||x||^2 in fp32
    ssA += va.x * va.x + va.y * va.y + va.z * va.z + va.w * va.w;
    ssB += vb.x * vb.x + vb.y * vb.y + vb.z * vb.z + vb.w * vb.w;
    *(ushort4*)&As[cur][rowA * 40 + kc] =
        make_ushort4(f2bf(va.x), f2bf(va.y), f2bf(va.z), f2bf(va.w));
    *(ushort4*)&As[cur][rowB * 40 + kc] =
        make_ushort4(f2bf(vb.x), f2bf(vb.y), f2bf(vb.z), f2bf(vb.w));

    // register-prefetch next step's A (hides HBM latency behind this step's MFMA)
    if (kk + 1 < STEPS) {
      va = *(const float4*)(xA + (kk + 1) * BK);
      vb = *(const float4*)(xB + (kk + 1) * BK);
    }

    // B fragments for this step: 8 coalesced 16B loads/lane, issued up-front
    // for max outstanding L2 requests (this stream is the kernel's bottleneck)
    const unsigned short* pbk = pb + ((size_t)(kk * 32 + wc * 8) * 64 + l) * 8;
    short8 b[8];
    #pragma unroll
    for (int ct = 0; ct < 8; ++ct)
      b[ct] = *(const short8*)(pbk + (size_t)ct * 64 * 8);

    __syncthreads();  // As[cur] staging visible (single barrier per K-step)

    short8 a[4];
    #pragma unroll
    for (int rt = 0; rt < 4; ++rt)
      a[rt] = *(const short8*)&As[cur][(wr * 64 + rt * 16 + (l & 15)) * 40 + (l >> 4) * 8];

    #pragma unroll
    for (int ct = 0; ct < 8; ++ct)
      #pragma unroll
      for (int rt = 0; rt < 4; ++rt)
        acc[rt][ct] = __builtin_amdgcn_mfma_f32_16x16x32_bf16(a[rt], b[ct], acc[rt][ct], 0, 0, 0);

    cur ^= 1;
  }

  // ||x||^2 per row: reduce within 8-lane groups (same row), fp32-exact
  float s1 = ssA, s2 = ssB;
  s1 += __shfl_xor(s1, 1); s1 += __shfl_xor(s1, 2); s1 += __shfl_xor(s1, 4);
  s2 += __shfl_xor(s2, 1); s2 += __shfl_xor(s2, 2); s2 += __shfl_xor(s2, 4);
  if ((t & 7) == 0) { x2s[rowA] = s1; x2s[rowB] = s2; }
  __syncthreads();

  const int lg = l >> 4;
  const int ln = l & 15;

  float xr[4][4];
  #pragma unroll
  for (int rt = 0; rt < 4; ++rt)
    #pragma unroll
    for (int r = 0; r < 4; ++r) xr[rt][r] = x2s[wr * 64 + rt * 16 + lg * 4 + r];
  float cv[8];
  #pragma unroll
  for (int ct = 0; ct < 8; ++ct) cv[ct] = c2s[wc * 128 + ct * 16 + ln];

  float rp[4][4];
  #pragma unroll
  for (int rt = 0; rt < 4; ++rt)
    #pragma unroll
    for (int r = 0; r < 4; ++r) rp[rt][r] = 0.f;

  #pragma unroll
  for (int rt = 0; rt < 4; ++rt)
    #pragma unroll
    for (int ct = 0; ct < 8; ++ct) {
      f32x4 s = acc[rt][ct], q;
      #pragma unroll
      for (int r = 0; r < 4; ++r) {
        float d2 = xr[rt][r] + cv[ct] - 2.f * s[r];
        d2 = fmaxf(d2, 0.f);
        float qq = __builtin_amdgcn_rcpf(1.f + d2);
        q[r] = qq;
        rp[rt][r] += qq;
      }
      acc[rt][ct] = q;
    }

  #pragma unroll
  for (int m = 1; m < 16; m <<= 1)
    #pragma unroll
    for (int rt = 0; rt < 4; ++rt)
      #pragma unroll
      for (int r = 0; r < 4; ++r) rp[rt][r] += __shfl_xor(rp[rt][r], m);

  if (ln == 0)
    #pragma unroll
    for (int rt = 0; rt < 4; ++rt)
      #pragma unroll
      for (int r = 0; r < 4; ++r)
        rowsum[wc][wr * 64 + rt * 16 + lg * 4 + r] = rp[rt][r];
  __syncthreads();

  if (t < M_TILE) {
    float tot = rowsum[0][t] + rowsum[1][t] + rowsum[2][t] + rowsum[3][t];
    rinv[t] = __builtin_amdgcn_rcpf(tot);
  }
  __syncthreads();

  float ri[4][4];
  #pragma unroll
  for (int rt = 0; rt < 4; ++rt)
    #pragma unroll
    for (int r = 0; r < 4; ++r) ri[rt][r] = rinv[wr * 64 + rt * 16 + lg * 4 + r];

  // nontemporal stores: keep the 268 MB write stream from evicting L2-resident pb
  #pragma unroll
  for (int rt = 0; rt < 4; ++rt)
    #pragma unroll
    for (int ct = 0; ct < 8; ++ct)
      #pragma unroll
      for (int r = 0; r < 4; ++r)
        __builtin_nontemporal_store(
            acc[rt][ct][r] * ri[rt][r],
            &out[(size_t)(row0 + wr * 64 + rt * 16 + lg * 4 + r) * K_CL + wc * 128 + ct * 16 + ln]);
}

extern "C" void kernel_launch(void* const* d_in, const int* in_sizes, int n_in,
                              void* d_out, int out_size, void* d_ws, size_t ws_size,
                              hipStream_t stream) {
  const float* x        = (const float*)d_in[0];
  const float* clusters = (const float*)d_in[1];
  float* out = (float*)d_out;

  // workspace: [pb: 512*512*2B packed bf16][c2: 512*4B]
  unsigned short* pbuf = (unsigned short*)d_ws;
  float* c2 = (float*)((char*)d_ws + (size_t)K_CL * D_DIM * sizeof(unsigned short));

  prep_c2<<<K_CL, 64, 0, stream>>>(clusters, c2);
  pack_b<<<STEPS * 32, 64, 0, stream>>>(clusters, pbuf);
  cluster_main<<<N_ROWS / M_TILE, 512, 0, stream>>>(x, pbuf, c2, out);
}